// Round 4
// baseline (286.904 us; speedup 1.0000x reference)
//
#include <hip/hip_runtime.h>
#include <hip/hip_bf16.h>

#define IN_N   8192
#define OUT_N  8186
#define KS     7

#define BXO    128            // output cols per block
#define BYO    32             // output rows per step
#define IC     144            // staged input cols
#define IR     38             // staged input rows = BYO + 6
#define LSTR   304            // LDS bytes/row (144*2 + 16 pad)
#define GPR    36             // float4 granules per staged row
#define NGRAN  (IR * GPR)     // 1368
#define NLD    6              // ceil(1368/256)
#define NSTEP  4
#define SEG_ROWS (BYO * NSTEP) // 128
#define NSEG   64
#define NSTRIP 64

typedef __bf16 bf16x8 __attribute__((ext_vector_type(8)));
typedef float  f32x4  __attribute__((ext_vector_type(4)));

union BFU { __bf16 h; unsigned short u; };
__device__ __forceinline__ unsigned short f2bf(float f) {
    BFU c; c.h = (__bf16)f; return c.u;
}

template<bool GUARD>
__device__ __forceinline__ void run_block(
    const float* __restrict__ X, const float* __restrict__ Kw,
    const float* __restrict__ bias, float* __restrict__ out,
    char* sb0, char* sb1, int X0, int ybase, int tid)
{
    const int lane = tid & 63;
    const int wv   = tid >> 6;         // 4 waves: 2 in y x 2 in x
    const int wy   = wv & 1;
    const int wx   = wv >> 1;
    const int lo   = lane & 15;
    const int hi   = lane >> 4;

    // constant Toeplitz B: B[k][j] = w[ky][k-j], k = 8*hi+e, j = lo.
    // A and B share the (lane,e)->k convention, so HW k-permutations cancel.
    bf16x8 bfrag[KS];
    #pragma unroll
    for (int ky = 0; ky < KS; ++ky) {
        bf16x8 bv;
        #pragma unroll
        for (int e = 0; e < 8; ++e) {
            const int d = 8*hi + e - lo;
            bv[e] = (__bf16)((d >= 0 && d < KS) ? Kw[ky*KS + d] : 0.0f);
        }
        bfrag[ky] = bv;
    }
    const float b = bias[0];

    // step-invariant staging coords
    int srow[NLD], scol[NLD];
    #pragma unroll
    for (int k = 0; k < NLD; ++k) {
        const int g = k*256 + tid;
        srow[k] = g / GPR;
        scol[k] = (g - srow[k]*GPR) * 4;
    }

    // ---- prologue: stage step-0 tile ----
    {
        float4 ld[NLD];
        #pragma unroll
        for (int k = 0; k < NLD; ++k) {
            if (k*256 + tid < NGRAN) {
                int r = ybase + srow[k], c = X0 + scol[k];
                if (GUARD) { r = min(r, IN_N-1); c = min(c, IN_N-4); }
                ld[k] = *(const float4*)(X + (size_t)r * IN_N + c);
            }
        }
        #pragma unroll
        for (int k = 0; k < NLD; ++k) {
            if (k*256 + tid < NGRAN) {
                ushort4 h;
                h.x = f2bf(ld[k].x); h.y = f2bf(ld[k].y);
                h.z = f2bf(ld[k].z); h.w = f2bf(ld[k].w);
                *(ushort4*)(sb0 + srow[k]*LSTR + scol[k]*2) = h;
            }
        }
    }
    asm volatile("s_waitcnt lgkmcnt(0)" ::: "memory");
    __builtin_amdgcn_s_barrier();
    __builtin_amdgcn_sched_barrier(0);

    #pragma unroll
    for (int t = 0; t < NSTEP; ++t) {
        char* cur = (t & 1) ? sb1 : sb0;
        char* nxt = (t & 1) ? sb0 : sb1;
        const int y0 = ybase + t * BYO;

        // issue next-tile loads EARLY (hide HBM latency under MFMA+stores)
        float4 ld[NLD];
        if (t + 1 < NSTEP) {
            const int yn = y0 + BYO;
            #pragma unroll
            for (int k = 0; k < NLD; ++k) {
                if (k*256 + tid < NGRAN) {
                    int r = yn + srow[k], c = X0 + scol[k];
                    if (GUARD) { r = min(r, IN_N-1); c = min(c, IN_N-4); }
                    ld[k] = *(const float4*)(X + (size_t)r * IN_N + c);
                }
            }
        }

        // compute: 4 x-tiles per wave, 7 MFMA each (2 independent acc chains)
        const char* abase = cur + (16*wy + lo) * LSTR + 128*wx + 16*hi;
        float* obase = out + (size_t)(y0 + 16*wy + 4*hi) * OUT_N + (X0 + 64*wx + lo);
        #pragma unroll
        for (int t8 = 0; t8 < 4; ++t8) {
            f32x4 accA = { b, b, b, b };
            f32x4 accB = { 0.f, 0.f, 0.f, 0.f };
            bf16x8 a0 = *(const bf16x8*)(abase + 0*LSTR + 32*t8);
            bf16x8 a1 = *(const bf16x8*)(abase + 1*LSTR + 32*t8);
            bf16x8 a2 = *(const bf16x8*)(abase + 2*LSTR + 32*t8);
            bf16x8 a3 = *(const bf16x8*)(abase + 3*LSTR + 32*t8);
            bf16x8 a4 = *(const bf16x8*)(abase + 4*LSTR + 32*t8);
            bf16x8 a5 = *(const bf16x8*)(abase + 5*LSTR + 32*t8);
            bf16x8 a6 = *(const bf16x8*)(abase + 6*LSTR + 32*t8);
            accA = __builtin_amdgcn_mfma_f32_16x16x32_bf16(a0, bfrag[0], accA, 0, 0, 0);
            accB = __builtin_amdgcn_mfma_f32_16x16x32_bf16(a1, bfrag[1], accB, 0, 0, 0);
            accA = __builtin_amdgcn_mfma_f32_16x16x32_bf16(a2, bfrag[2], accA, 0, 0, 0);
            accB = __builtin_amdgcn_mfma_f32_16x16x32_bf16(a3, bfrag[3], accB, 0, 0, 0);
            accA = __builtin_amdgcn_mfma_f32_16x16x32_bf16(a4, bfrag[4], accA, 0, 0, 0);
            accB = __builtin_amdgcn_mfma_f32_16x16x32_bf16(a5, bfrag[5], accB, 0, 0, 0);
            accA = __builtin_amdgcn_mfma_f32_16x16x32_bf16(a6, bfrag[6], accA, 0, 0, 0);
            const f32x4 acc = accA + accB;

            if (GUARD) {
                const int ox = X0 + 64*wx + 16*t8 + lo;
                if (ox < OUT_N) {
                    #pragma unroll
                    for (int r = 0; r < 4; ++r) {
                        const int oy = y0 + 16*wy + 4*hi + r;
                        if (oy < OUT_N) obase[(size_t)r*OUT_N + 16*t8] = acc[r];
                    }
                }
            } else {
                #pragma unroll
                for (int r = 0; r < 4; ++r)
                    obase[(size_t)r*OUT_N + 16*t8] = acc[r];
            }
        }

        // convert + LDS-write next tile; one barrier per step, stores stay in flight
        if (t + 1 < NSTEP) {
            #pragma unroll
            for (int k = 0; k < NLD; ++k) {
                if (k*256 + tid < NGRAN) {
                    ushort4 h;
                    h.x = f2bf(ld[k].x); h.y = f2bf(ld[k].y);
                    h.z = f2bf(ld[k].z); h.w = f2bf(ld[k].w);
                    *(ushort4*)(nxt + srow[k]*LSTR + scol[k]*2) = h;
                }
            }
            asm volatile("s_waitcnt lgkmcnt(0)" ::: "memory");
            __builtin_amdgcn_s_barrier();
            __builtin_amdgcn_sched_barrier(0);
        }
    }
}

__global__ __launch_bounds__(256, 6)
void conv7x7_mfma(const float* __restrict__ X, const float* __restrict__ Kw,
                  const float* __restrict__ bias, float* __restrict__ out) {
    __shared__ __align__(16) char sb[2][IR * LSTR];   // 2 x 11552 B = 23.1 KB -> 6 blocks/CU
    const int tid = threadIdx.x;

    // bijective XCD swizzle: 4096 blocks, 512 per XCD, contiguous band per XCD
    const int bid = blockIdx.x;
    const int swz = (bid & 7) * (NSTRIP * NSEG / 8) + (bid >> 3);
    const int strip = swz & (NSTRIP - 1);
    const int seg   = swz >> 6;
    const int X0    = strip * BXO;
    const int ybase = seg * SEG_ROWS;

    if (strip == NSTRIP-1 || seg == NSEG-1)
        run_block<true >(X, Kw, bias, out, sb[0], sb[1], X0, ybase, tid);
    else
        run_block<false>(X, Kw, bias, out, sb[0], sb[1], X0, ybase, tid);
}

extern "C" void kernel_launch(void* const* d_in, const int* in_sizes, int n_in,
                              void* d_out, int out_size, void* d_ws, size_t ws_size,
                              hipStream_t stream) {
    const float* X    = (const float*)d_in[0];
    const float* Kw   = (const float*)d_in[1];
    const float* bias = (const float*)d_in[2];
    float* out = (float*)d_out;

    conv7x7_mfma<<<dim3(NSTRIP * NSEG), dim3(256), 0, stream>>>(X, Kw, bias, out);
}

// Round 5
// 153.232 us; speedup vs baseline: 1.8723x; 1.8723x over previous
//
#include <hip/hip_runtime.h>
#include <hip/hip_bf16.h>

#define IN_N    8192
#define OUT_N   8186
#define KS      7

#define BXO     128           // output cols per block
#define BYO     64            // output rows per step
#define IC      144           // staged input cols (A reads k to 31 past col 112)
#define IR      70            // staged input rows = BYO + 6
#define F32_STR 576           // fp32 LDS row stride bytes (36 granules, dense)
#define B16_STR 304           // bf16 LDS row stride bytes (2-way max bank profile)
#define GPR     36            // 16B granules per fp32 row
#define NGRAN   (IR * GPR)    // 2520
#define NRND    10            // ceil(2520/256)
#define NSTEP   4
#define SEG_ROWS (BYO * NSTEP) // 256
#define NSEG    32
#define NSTRIP  64

typedef __bf16 bf16x8 __attribute__((ext_vector_type(8)));
typedef float  f32x4  __attribute__((ext_vector_type(4)));

union BFU { __bf16 h; unsigned short u; };
__device__ __forceinline__ unsigned short f2bf(float f) {
    BFU c; c.h = (__bf16)f; return c.u;
}

typedef const __attribute__((address_space(1))) unsigned int* gas1_t;
typedef __attribute__((address_space(3))) unsigned int* las3_t;
__device__ __forceinline__ void gll16(const float* g, char* l) {
    // LDS dest: wave-uniform base + lane*16; global src per-lane.
    __builtin_amdgcn_global_load_lds((gas1_t)(const void*)g, (las3_t)(void*)l, 16, 0, 0);
}

// issue 10 async fp32 granule loads per wave into sF (linear layout)
__device__ __forceinline__ void stage_gll(const float* Xs, char* sF,
                                          const int* srow, const int* scol, int tid) {
    #pragma unroll
    for (int k = 0; k < NRND; ++k) {
        if (k * 256 + tid < NGRAN)
            gll16(Xs + (size_t)srow[k] * IN_N + scol[k],
                  sF + (size_t)(k * 256 + (tid & ~63)) * 16);
    }
}

// LDS fp32 -> bf16 tile (1x conversion per element)
__device__ __forceinline__ void cvt_phase(const char* sF, char* sB,
                                          const int* srow, const int* scol, int tid) {
    #pragma unroll
    for (int k = 0; k < NRND; ++k) {
        const int g = k * 256 + tid;
        if (g < NGRAN) {
            f32x4 v = *(const f32x4*)(sF + (size_t)g * 16);
            ushort4 h;
            h.x = f2bf(v[0]); h.y = f2bf(v[1]);
            h.z = f2bf(v[2]); h.w = f2bf(v[3]);
            *(ushort4*)(sB + srow[k] * B16_STR + scol[k] * 2) = h;
        }
    }
}

template<bool GUARD>
__device__ __forceinline__ void compute_store(
    const char* sB, const bf16x8* bfrag, float b, float* __restrict__ out,
    int y0, int X0, int lo, int hi, int wv)
{
    // wave wv owns rows 16wv..16wv+15, FULL 128-col span (512B rows -> clean line completion)
    const char* abase = sB + (16*wv + lo) * B16_STR + 16*hi;
    float* obase = out + (size_t)(y0 + 16*wv + 4*hi) * OUT_N + (X0 + lo);
    #pragma unroll
    for (int t8 = 0; t8 < 8; ++t8) {
        f32x4 accA = { b, b, b, b };
        f32x4 accB = { 0.f, 0.f, 0.f, 0.f };
        bf16x8 a0 = *(const bf16x8*)(abase + 0*B16_STR + 32*t8);
        bf16x8 a1 = *(const bf16x8*)(abase + 1*B16_STR + 32*t8);
        bf16x8 a2 = *(const bf16x8*)(abase + 2*B16_STR + 32*t8);
        bf16x8 a3 = *(const bf16x8*)(abase + 3*B16_STR + 32*t8);
        bf16x8 a4 = *(const bf16x8*)(abase + 4*B16_STR + 32*t8);
        bf16x8 a5 = *(const bf16x8*)(abase + 5*B16_STR + 32*t8);
        bf16x8 a6 = *(const bf16x8*)(abase + 6*B16_STR + 32*t8);
        accA = __builtin_amdgcn_mfma_f32_16x16x32_bf16(a0, bfrag[0], accA, 0, 0, 0);
        accB = __builtin_amdgcn_mfma_f32_16x16x32_bf16(a1, bfrag[1], accB, 0, 0, 0);
        accA = __builtin_amdgcn_mfma_f32_16x16x32_bf16(a2, bfrag[2], accA, 0, 0, 0);
        accB = __builtin_amdgcn_mfma_f32_16x16x32_bf16(a3, bfrag[3], accB, 0, 0, 0);
        accA = __builtin_amdgcn_mfma_f32_16x16x32_bf16(a4, bfrag[4], accA, 0, 0, 0);
        accB = __builtin_amdgcn_mfma_f32_16x16x32_bf16(a5, bfrag[5], accB, 0, 0, 0);
        accA = __builtin_amdgcn_mfma_f32_16x16x32_bf16(a6, bfrag[6], accA, 0, 0, 0);
        const f32x4 acc = accA + accB;

        if (GUARD) {
            const int ox = X0 + 16*t8 + lo;
            if (ox < OUT_N) {
                #pragma unroll
                for (int r = 0; r < 4; ++r) {
                    const int oy = y0 + 16*wv + 4*hi + r;
                    if (oy < OUT_N) obase[(size_t)r * OUT_N + 16*t8] = acc[r];
                }
            }
        } else {
            #pragma unroll
            for (int r = 0; r < 4; ++r)
                obase[(size_t)r * OUT_N + 16*t8] = acc[r];
        }
    }
}

__global__ __launch_bounds__(256, 2)
void conv7x7_dma(const float* __restrict__ X, const float* __restrict__ Kw,
                 const float* __restrict__ bias, float* __restrict__ out) {
    __shared__ __align__(16) char sF[IR * F32_STR];   // 40320 B fp32 stage (DMA target)
    __shared__ __align__(16) char sB[IR * B16_STR];   // 21280 B bf16 tile
    const int tid  = threadIdx.x;
    const int lane = tid & 63;
    const int wv   = tid >> 6;
    const int lo   = lane & 15;
    const int hi   = lane >> 4;

    // bijective XCD swizzle: 2048 blocks, 256/XCD; within XCD walk strips first (x-halo L2 reuse)
    const int bid   = blockIdx.x;
    const int swz   = (bid & 7) * (NSTRIP * NSEG / 8) + (bid >> 3);
    const int strip = swz & (NSTRIP - 1);
    const int seg   = swz >> 6;
    const int X0    = strip * BXO;
    const int ybase = seg * SEG_ROWS;

    // constant Toeplitz B: B[k][j] = w[ky][k-j], k = 8*hi+e, j = lo.
    // A and B share the (lane,e)->k convention, so HW k-permutations cancel.
    bf16x8 bfrag[KS];
    #pragma unroll
    for (int ky = 0; ky < KS; ++ky) {
        bf16x8 bv;
        #pragma unroll
        for (int e = 0; e < 8; ++e) {
            const int d = 8*hi + e - lo;
            bv[e] = (__bf16)((d >= 0 && d < KS) ? Kw[ky*KS + d] : 0.0f);
        }
        bfrag[ky] = bv;
    }
    const float b = bias[0];

    // step-invariant granule coords
    int srow[NRND], scol[NRND];
    #pragma unroll
    for (int k = 0; k < NRND; ++k) {
        const int g = k * 256 + tid;
        srow[k] = g / GPR;
        scol[k] = (g - srow[k] * GPR) * 4;
    }

    if (strip < NSTRIP - 1 && seg < NSEG - 1) {
        // -------- interior: async DMA pipeline --------
        stage_gll(X + (size_t)ybase * IN_N + X0, sF, srow, scol, tid);
        asm volatile("s_waitcnt vmcnt(0)" ::: "memory");
        __builtin_amdgcn_s_barrier();
        __builtin_amdgcn_sched_barrier(0);

        #pragma unroll
        for (int t = 0; t < NSTEP; ++t) {
            cvt_phase(sF, sB, srow, scol, tid);
            asm volatile("s_waitcnt lgkmcnt(0)" ::: "memory");
            __builtin_amdgcn_s_barrier();
            __builtin_amdgcn_sched_barrier(0);

            if (t + 1 < NSTEP) {
                // sF fully consumed by cvt; start DMA for t+1 under compute(t)
                stage_gll(X + (size_t)(ybase + (t+1)*BYO) * IN_N + X0, sF, srow, scol, tid);
                __builtin_amdgcn_sched_barrier(0);
            }

            compute_store<false>(sB, bfrag, b, out, ybase + t*BYO, X0, lo, hi, wv);

            if (t + 1 < NSTEP) {
                // per wave outstanding: [32 stores(t-1)] [10 glls(t+1)] [32 stores(t)]
                // vmcnt(32) retires the 42 oldest = old stores + glls; new stores keep flowing
                asm volatile("s_waitcnt vmcnt(32)" ::: "memory");
                __builtin_amdgcn_s_barrier();
                __builtin_amdgcn_sched_barrier(0);
            }
        }
    } else {
        // -------- boundary (~4.6% of blocks): simple guarded path --------
        for (int t = 0; t < NSTEP; ++t) {
            const int y0s = ybase + t * BYO;
            __syncthreads();
            #pragma unroll
            for (int k = 0; k < NRND; ++k) {
                const int g = k * 256 + tid;
                if (g < NGRAN) {
                    const int r = min(y0s + srow[k], IN_N - 1);
                    const int c = min(X0 + scol[k], IN_N - 4);  // clamped junk only feeds discarded outputs
                    float4 v = *(const float4*)(X + (size_t)r * IN_N + c);
                    ushort4 h;
                    h.x = f2bf(v.x); h.y = f2bf(v.y);
                    h.z = f2bf(v.z); h.w = f2bf(v.w);
                    *(ushort4*)(sB + srow[k] * B16_STR + scol[k] * 2) = h;
                }
            }
            __syncthreads();
            compute_store<true>(sB, bfrag, b, out, y0s, X0, lo, hi, wv);
        }
    }
}

extern "C" void kernel_launch(void* const* d_in, const int* in_sizes, int n_in,
                              void* d_out, int out_size, void* d_ws, size_t ws_size,
                              hipStream_t stream) {
    const float* X    = (const float*)d_in[0];
    const float* Kw   = (const float*)d_in[1];
    const float* bias = (const float*)d_in[2];
    float* out = (float*)d_out;

    conv7x7_dma<<<dim3(NSTRIP * NSEG), dim3(256), 0, stream>>>(X, Kw, bias, out);
}

// Round 6
// 148.729 us; speedup vs baseline: 1.9290x; 1.0303x over previous
//
#include <hip/hip_runtime.h>
#include <hip/hip_bf16.h>

#define IN_N   8192
#define OUT_N  8186
#define KS     7

#define WX     112             // output cols per chunk
#define SROW   22              // staged rows per band (16 out + 6 halo)
#define NLDW   11              // 16B-granule load rounds per wave (22*32/64)
#define LSTR   272             // LDS bytes per staged row (128 bf16 = 256B + 16 pad)
#define WAVE_LDS (SROW * LSTR) // 5984 B per wave
#define NCHUNK 5               // chunks per panel
#define NPANEL 15              // panels across x (15*5*112 = 8400 >= 8186)
#define NGROUP 128             // band groups (4 bands/block): 512 bands of 16 rows
#define NBLK   (NGROUP * NPANEL) // 1920 blocks
#define GCHUNK 73              // last (partial) chunk index: 73*112 = 8176 < 8186

typedef __bf16 bf16x8 __attribute__((ext_vector_type(8)));
typedef float  f32x4  __attribute__((ext_vector_type(4)));

union BFU { __bf16 h; unsigned short u; };
__device__ __forceinline__ unsigned short f2bf(float f) {
    BFU c; c.h = (__bf16)f; return c.u;
}

template<bool G>
struct WavePipe {
    const float* X; float* out;
    char* sb;                 // wave-private LDS tile
    int y0;                   // first output row of this band
    int lo, hi, ls5, l31;
    float bv;
    bf16x8 bfrag[KS];
    float4 ld[NLDW];          // in-flight chunk (statically indexed everywhere)

    __device__ __forceinline__ void load_chunk(int c) {
        const int xb = c * WX;
        if constexpr (!G) {
            const float* gb = X + (size_t)(y0 + ls5) * IN_N + xb + l31 * 4;
            #pragma unroll
            for (int k = 0; k < NLDW; ++k)
                ld[k] = *(const float4*)(gb + (size_t)(2 * k) * IN_N);
        } else {
            #pragma unroll
            for (int k = 0; k < NLDW; ++k) {
                const int r  = min(y0 + ls5 + 2 * k, IN_N - 1);
                const int cc = min(xb + l31 * 4, IN_N - 4);  // clamped junk only feeds discarded outputs
                ld[k] = *(const float4*)(X + (size_t)r * IN_N + cc);
            }
        }
    }

    __device__ __forceinline__ void write_chunk() {
        char* lb = sb + ls5 * LSTR + l31 * 8;
        #pragma unroll
        for (int k = 0; k < NLDW; ++k) {
            ushort4 h;
            h.x = f2bf(ld[k].x); h.y = f2bf(ld[k].y);
            h.z = f2bf(ld[k].z); h.w = f2bf(ld[k].w);
            *(ushort4*)(lb + k * 544) = h;   // 544 = 2*LSTR (row advances 2 per round)
        }
    }

    __device__ __forceinline__ void compute_chunk(int c) {
        const int xb = c * WX;
        const char* ab = sb + lo * LSTR + 16 * hi;
        float* ob = out + (size_t)(y0 + 4 * hi) * OUT_N + xb + lo;
        #pragma unroll
        for (int t8 = 0; t8 < 7; ++t8) {
            f32x4 accA = { bv, bv, bv, bv };
            f32x4 accB = { 0.f, 0.f, 0.f, 0.f };
            bf16x8 a0 = *(const bf16x8*)(ab + 0*LSTR + 32*t8);
            bf16x8 a1 = *(const bf16x8*)(ab + 1*LSTR + 32*t8);
            bf16x8 a2 = *(const bf16x8*)(ab + 2*LSTR + 32*t8);
            bf16x8 a3 = *(const bf16x8*)(ab + 3*LSTR + 32*t8);
            bf16x8 a4 = *(const bf16x8*)(ab + 4*LSTR + 32*t8);
            bf16x8 a5 = *(const bf16x8*)(ab + 5*LSTR + 32*t8);
            bf16x8 a6 = *(const bf16x8*)(ab + 6*LSTR + 32*t8);
            accA = __builtin_amdgcn_mfma_f32_16x16x32_bf16(a0, bfrag[0], accA, 0, 0, 0);
            accB = __builtin_amdgcn_mfma_f32_16x16x32_bf16(a1, bfrag[1], accB, 0, 0, 0);
            accA = __builtin_amdgcn_mfma_f32_16x16x32_bf16(a2, bfrag[2], accA, 0, 0, 0);
            accB = __builtin_amdgcn_mfma_f32_16x16x32_bf16(a3, bfrag[3], accB, 0, 0, 0);
            accA = __builtin_amdgcn_mfma_f32_16x16x32_bf16(a4, bfrag[4], accA, 0, 0, 0);
            accB = __builtin_amdgcn_mfma_f32_16x16x32_bf16(a5, bfrag[5], accB, 0, 0, 0);
            accA = __builtin_amdgcn_mfma_f32_16x16x32_bf16(a6, bfrag[6], accA, 0, 0, 0);
            const f32x4 acc = accA + accB;

            if constexpr (!G) {
                #pragma unroll
                for (int r = 0; r < 4; ++r)
                    ob[(size_t)r * OUT_N + 16 * t8] = acc[r];
            } else {
                const int ox = xb + 16 * t8 + lo;
                if (ox < OUT_N) {
                    #pragma unroll
                    for (int r = 0; r < 4; ++r) {
                        const int oy = y0 + 4 * hi + r;
                        if (oy < OUT_N) ob[(size_t)r * OUT_N + 16 * t8] = acc[r];
                    }
                }
            }
        }
    }

    __device__ __forceinline__ void run(int c0, int nc) {
        // prologue: stage first chunk (compiler inserts vmcnt waits for ld use)
        load_chunk(c0);
        write_chunk();
        asm volatile("s_waitcnt lgkmcnt(0)" ::: "memory");
        __builtin_amdgcn_sched_barrier(0);

        for (int i = 0; i < nc; ++i) {
            const int c = c0 + i;
            const bool pre = (i + 1 < nc);
            if (pre) load_chunk(c + 1);          // HBM latency hides under compute
            __builtin_amdgcn_sched_barrier(0);
            compute_chunk(c);
            __builtin_amdgcn_sched_barrier(0);
            if (pre) {
                asm volatile("s_waitcnt lgkmcnt(0)" ::: "memory"); // own ds_reads retired
                write_chunk();
                asm volatile("s_waitcnt lgkmcnt(0)" ::: "memory"); // writes visible to own reads
                __builtin_amdgcn_sched_barrier(0);
            }
        }
    }
};

__global__ __launch_bounds__(256, 4)
void conv7x7_wp(const float* __restrict__ X, const float* __restrict__ Kw,
                const float* __restrict__ bias, float* __restrict__ out) {
    __shared__ __align__(16) char sb_all[4 * WAVE_LDS];   // 23936 B

    const int tid  = threadIdx.x;
    const int lane = tid & 63;
    const int wv   = tid >> 6;

    // bijective XCD swizzle (1920 % 8 == 0): each XCD gets a contiguous band range
    const int bid  = blockIdx.x;
    const int swz  = (bid & 7) * (NBLK / 8) + (bid >> 3);
    const int grp  = swz / NPANEL;
    const int pan  = swz - grp * NPANEL;
    const int band = grp * 4 + wv;           // 0..511; adjacent bands share halo via L1/L2

    const int c0 = pan * NCHUNK;
    const int nc = min(NCHUNK, (OUT_N - c0 * WX + WX - 1) / WX);

    WavePipe<false> wp;   // layout identical for both paths; G chosen below
    // common init
    const int lo = lane & 15, hi = lane >> 4;
    // Toeplitz B: B[k][j] = w[ky][k-j], k = 8*hi+e, j = lo.
    // A and B share the (lane,e)->k convention, so HW k-permutations cancel.
    bf16x8 bfrag[KS];
    #pragma unroll
    for (int ky = 0; ky < KS; ++ky) {
        bf16x8 bvv;
        #pragma unroll
        for (int e = 0; e < 8; ++e) {
            const int d = 8 * hi + e - lo;
            bvv[e] = (__bf16)((d >= 0 && d < KS) ? Kw[ky * KS + d] : 0.0f);
        }
        bfrag[ky] = bvv;
    }

    const bool guarded = (band == NGROUP * 4 - 1) || (pan == NPANEL - 1);

    if (!guarded) {
        WavePipe<false> p;
        p.X = X; p.out = out; p.sb = sb_all + wv * WAVE_LDS;
        p.y0 = band * 16; p.lo = lo; p.hi = hi;
        p.ls5 = lane >> 5; p.l31 = lane & 31; p.bv = bias[0];
        #pragma unroll
        for (int k = 0; k < KS; ++k) p.bfrag[k] = bfrag[k];
        p.run(c0, nc);
    } else {
        WavePipe<true> p;
        p.X = X; p.out = out; p.sb = sb_all + wv * WAVE_LDS;
        p.y0 = band * 16; p.lo = lo; p.hi = hi;
        p.ls5 = lane >> 5; p.l31 = lane & 31; p.bv = bias[0];
        #pragma unroll
        for (int k = 0; k < KS; ++k) p.bfrag[k] = bfrag[k];
        p.run(c0, nc);
    }
}

extern "C" void kernel_launch(void* const* d_in, const int* in_sizes, int n_in,
                              void* d_out, int out_size, void* d_ws, size_t ws_size,
                              hipStream_t stream) {
    const float* X    = (const float*)d_in[0];
    const float* Kw   = (const float*)d_in[1];
    const float* bias = (const float*)d_in[2];
    float* out = (float*)d_out;

    conv7x7_wp<<<dim3(NBLK), dim3(256), 0, stream>>>(X, Kw, bias, out);
}